// Round 6
// baseline (94.312 us; speedup 1.0000x reference)
//
#include <hip/hip_runtime.h>
#include <hip/hip_fp16.h>

#define NN 2048

typedef _Float16 f16x8 __attribute__((ext_vector_type(8)));
typedef float f32x4 __attribute__((ext_vector_type(4)));

// ---------------------------------------------------------------------------
// Prep: proj = A@Wp.T + bp  (2048x32), then
//       pa'  = proj@Wa.T + b1  (f16, b1 folded),  pb = proj@Wb.T (f16)
// ---------------------------------------------------------------------------
__global__ __launch_bounds__(256) void prep_kernel(
    const float* __restrict__ A, const float* __restrict__ Wp,
    const float* __restrict__ bp, const float* __restrict__ W1,
    const float* __restrict__ b1,
    _Float16* __restrict__ pa, _Float16* __restrict__ pb)
{
    __shared__ float projLDS[8][32];
    const int t = threadIdx.x;
    const int rl = t >> 5;        // local row 0..7
    const int k  = t & 31;        // output unit 0..31
    const int row = blockIdx.x * 8 + rl;

    const float4* xa = (const float4*)(A + row * 64);
    const float4* wp = (const float4*)(Wp + k * 64);
    float acc = bp[k];
#pragma unroll
    for (int m = 0; m < 16; ++m) {
        float4 xv = xa[m], wv = wp[m];
        acc += xv.x * wv.x + xv.y * wv.y + xv.z * wv.z + xv.w * wv.w;
    }
    projLDS[rl][k] = acc;
    __syncthreads();

    const float4* w1a = (const float4*)(W1 + k * 64);        // m = 0..31
    const float4* w1b = (const float4*)(W1 + k * 64 + 32);   // m = 32..63
    const float4* pr  = (const float4*)(projLDS[rl]);
    float sa = b1[k], sb = 0.f;
#pragma unroll
    for (int m = 0; m < 8; ++m) {
        float4 p = pr[m], wa = w1a[m], wb = w1b[m];
        sa += p.x * wa.x + p.y * wa.y + p.z * wa.z + p.w * wa.w;
        sb += p.x * wb.x + p.y * wb.y + p.z * wb.z + p.w * wb.w;
    }
    pa[row * 32 + k] = (_Float16)sa;
    pb[row * 32 + k] = (_Float16)sb;
}

// ---------------------------------------------------------------------------
// Main (16x16x32 MFMA): one wave owns a 32i x 16j tile; 4 waves/block share
// the 32-row pa tile (2 KB LDS).  Per i:
//   D[h=16][pair=16] = A(W2, 16x32, fully used) . B(h1, 32x16), k=32, 1 MFMA,
//   C preloaded with b2 (f32x4!).
// Fragment maps: A row m = lane&15, k = (lane>>4)*8+e; B col n = lane&15,
// same k map -> common k-permutation cancels (validated R2-R5 at 2e-3).
// C/D [m89-verified]: col = lane&15, row = (lane>>4)*4 + r.
// Epilogue per i: 4 relu-fma (lane's 4 h's) then butterfly over lane>>4
// (xor16 + xor32). Every 4 i's: lane q=lane>>4 takes s[q] -> full-wave
// sigmoid + diag + coalesced 64-output store.
// Low VGPR (~55) -> __launch_bounds__(256,8): 8 waves/SIMD, 2x latency hiding
// vs R5 (sim was latency-bound: static VALU count ~4-5us vs measured ~11.5).
// ---------------------------------------------------------------------------
__global__ __launch_bounds__(256, 8) void sim_kernel(
    const _Float16* __restrict__ pa, const _Float16* __restrict__ pb,
    const float* __restrict__ W2, const float* __restrict__ b2,
    const float* __restrict__ W3, const float* __restrict__ b3,
    float* __restrict__ out)
{
    __shared__ _Float16 paLDS[32 * 32];
    const int t    = threadIdx.x;
    const int lane = t & 63;
    const int wid  = t >> 6;                              // wave 0..3
    const int i0 = (blockIdx.x >> 5) * 32;                // 64 i-tiles of 32
    const int jb = (((blockIdx.x & 31) << 2) + wid) * 16; // 128 j-tiles of 16
    const int n  = lane & 15;                             // pair column
    const int q  = lane >> 4;                             // k-group / h-group

    // stage pa i-tile: 1024 halves = 2 KB, 8 B/thread
    ((uint2*)paLDS)[t] = ((const uint2*)(pa + (size_t)i0 * 32))[t];

    // B-fragment source: pb[jb+n][q*8 + e]
    const f16x8 pbf = *(const f16x8*)(pb + (size_t)(jb + n) * 32 + q * 8);

    // A-fragment: W2[m=n][k=q*8+e], cvt f32->f16
    f16x8 w2f;
    {
        const float* w2r = W2 + n * 32 + q * 8;
#pragma unroll
        for (int e = 0; e < 8; ++e) w2f[e] = (_Float16)w2r[e];
    }

    // C-init (b2) and W3 following D row map: row = q*4 + r
    f32x4 cinit;
    float w3r[4];
#pragma unroll
    for (int r = 0; r < 4; ++r) {
        cinit[r] = b2[q * 4 + r];
        w3r[r]   = W3[q * 4 + r];
    }
    const float b3v = b3[0];
    const f16x8 zero = {};

    __syncthreads();

    // lane's output: row i0 + 4*tt + q, col jb + n
    float* outp = out + (size_t)(i0 + q) * NN + jb + n;

#pragma unroll 2
    for (int tt = 0; tt < 8; ++tt) {
        float s0, s1, s2, s3;
#pragma unroll
        for (int r4 = 0; r4 < 4; ++r4) {
            const int ii = 4 * tt + r4;
            f16x8 af = *(const f16x8*)&paLDS[ii * 32 + q * 8];     // broadcast
            f16x8 h1 = __builtin_elementwise_max(af + pbf, zero);  // relu(pa'+pb)
            f32x4 d = __builtin_amdgcn_mfma_f32_16x16x32_f16(w2f, h1, cinit, 0, 0, 0);
            float p = 0.f;
#pragma unroll
            for (int r = 0; r < 4; ++r)
                p = fmaf(fmaxf(d[r], 0.f), w3r[r], p);
            p += __shfl_xor(p, 16, 64);   // reduce over the 4 h-groups
            p += __shfl_xor(p, 32, 64);
            if (r4 == 0) s0 = p; else if (r4 == 1) s1 = p;
            else if (r4 == 2) s2 = p; else s3 = p;
        }
        // full-wave epilogue: lane q picks its i's logit
        const float z = (q < 2 ? (q == 0 ? s0 : s1) : (q == 2 ? s2 : s3)) + b3v;
        float sim = __builtin_amdgcn_rcpf(1.f + __expf(-z));
        const int iMine = i0 + 4 * tt + q;
        if (iMine == jb + n) sim = 1.f;
        outp[(size_t)(4 * tt) * NN] = sim;   // 64 unique outputs, full exec
    }
}

extern "C" void kernel_launch(void* const* d_in, const int* in_sizes, int n_in,
                              void* d_out, int out_size, void* d_ws, size_t ws_size,
                              hipStream_t stream)
{
    const float* A  = (const float*)d_in[0];
    const float* Wp = (const float*)d_in[1];
    const float* bp = (const float*)d_in[2];
    const float* W1 = (const float*)d_in[3];
    const float* b1 = (const float*)d_in[4];
    const float* W2 = (const float*)d_in[5];
    const float* b2 = (const float*)d_in[6];
    const float* W3 = (const float*)d_in[7];
    const float* b3 = (const float*)d_in[8];
    float* out = (float*)d_out;

    _Float16* pa = (_Float16*)d_ws;        // 2048*32 f16 = 128 KB
    _Float16* pb = pa + NN * 32;           // next 128 KB

    prep_kernel<<<NN / 8, 256, 0, stream>>>(A, Wp, bp, W1, b1, pa, pb);
    sim_kernel<<<2048, 256, 0, stream>>>(pa, pb, W2, b2, W3, b3, out);
}